// Round 16
// baseline (23938.309 us; speedup 1.0000x reference)
//
#include <hip/hip_runtime.h>

// LSTM-CRF on MI355X.
// Pipeline: gemm(gin L0, embed fused) -> [MERGED: lstm L0 + gin-L1 GEMM workers]
//           -> lstm L1 -> feats -> viterbi.
// Recurrence: round-13 PROVEN lstm (device-scope mailbox, simple spin). XCD-local comm
// is dead (rounds 2/3/14). Round-16: 192 worker blocks compute gin L1 DURING lstm L0,
// gated by a per-WG progress array (RELEASE publish every 32 steps / ACQUIRE poll).
// Gating also protects the shared gin buffer: prog0>=r means fwd-lstm consumed
// gin-L0 row r before workers overwrite it with gin-L1; same for bwd. 256 blocks
// <= 256 CUs at <=128 VGPR -> all resident -> no worker can starve the lstm.

#define T_SEQ 4096
#define HPAD  512
#define NTAG  16

// ---------------- workspace layout (bytes) ----------------
// prog : [64] i32 + ticket i32   @ 0          (in dead x0 region)
// x1   : [4096][1024] f32  16777216  @ 8388608
// x2   : [4096][1024] f32  16777216  @ 25165824
// gin  : [2][4096][2048] f32 67108864 @ 41943040
// feats: [4096][16] f32     262144  @ 109051904
// bptr : [4096][16] i32     262144  @ 109314048
// hcomm: [2][2][512] u64     16384  @ 109576192

// G[dir][t][n] = sum_k A[t][k] * Wmap[dir][n][k] + bias[n]
// 128x128 tile, 8x8/thread, double-buffered LDS. L0 mode: A = embed_w[sent[t]].
__global__ __launch_bounds__(256) void gin_gemm_k(
    const float* __restrict__ A, int KA,
    const int* __restrict__ sent, const float* __restrict__ embed_w,
    const float* __restrict__ wih, const float* __restrict__ bih,
    const float* __restrict__ bhh, int Kreal, float* __restrict__ G) {
  const int dir = blockIdx.z;
  const int bm = blockIdx.y, bn = blockIdx.x;
  const float* W = wih + (size_t)dir * 2000 * Kreal;

  __shared__ float As[2][16][128];
  __shared__ float Bs[2][16][128];
  __shared__ int   sSent[128];

  const int tid = threadIdx.x;
  const int tx = tid & 15, ty = tid >> 4;

  if (sent && tid < 128) sSent[tid] = sent[bm * 128 + tid];
  if (sent) __syncthreads();

  const int mA[2] = { (tid + 0) >> 2, (tid + 256) >> 2 };
  const int kA[2] = { ((tid + 0) & 3) * 4, ((tid + 256) & 3) * 4 };

  auto loadA = [&](int k0, int q) -> float4 {
    int m = mA[q], kc = kA[q];
    int k = k0 + kc;
    if (sent) {
      float4 z = {0.f, 0.f, 0.f, 0.f};
      if (k < 500)
        z = *reinterpret_cast<const float4*>(&embed_w[(size_t)sSent[m] * 500 + k]);
      return z;
    }
    return *reinterpret_cast<const float4*>(&A[(size_t)(bm * 128 + m) * KA + k]);
  };
  auto loadB = [&](int k0, int q) -> float4 {
    int n = mA[q], kc = kA[q];
    int nn = bn * 128 + n;
    int gate = nn >> 9, j = nn & 511;
    int k = k0 + kc;
    int jk = k & 511, half = k >> 9;
    float4 z = {0.f, 0.f, 0.f, 0.f};
    if (j < 500 && jk < 500)
      z = *reinterpret_cast<const float4*>(
          &W[(size_t)(gate * 500 + j) * Kreal + half * 500 + jk]);
    return z;
  };
  auto store = [&](int buf, int q, float4 av, float4 bv) {
    int m = mA[q], kc = kA[q];
    As[buf][kc + 0][m] = av.x; As[buf][kc + 1][m] = av.y;
    As[buf][kc + 2][m] = av.z; As[buf][kc + 3][m] = av.w;
    Bs[buf][kc + 0][m] = bv.x; Bs[buf][kc + 1][m] = bv.y;
    Bs[buf][kc + 2][m] = bv.z; Bs[buf][kc + 3][m] = bv.w;
  };

  {
    float4 a0 = loadA(0, 0), b0 = loadB(0, 0);
    float4 a1 = loadA(0, 1), b1 = loadB(0, 1);
    store(0, 0, a0, b0);
    store(0, 1, a1, b1);
  }
  __syncthreads();

  const int iters = KA >> 4;
  float acc[8][8] = {};

  for (int it = 0; it < iters; ++it) {
    const int cur = it & 1;
    const bool hasNext = (it + 1 < iters);
    float4 aP0, bP0, aP1, bP1;
    if (hasNext) {
      int k0n = (it + 1) << 4;
      aP0 = loadA(k0n, 0); bP0 = loadB(k0n, 0);
      aP1 = loadA(k0n, 1); bP1 = loadB(k0n, 1);
    }
#pragma unroll
    for (int kk = 0; kk < 16; kk++) {
      float a[8], b[8];
      *reinterpret_cast<float4*>(&a[0]) = *reinterpret_cast<const float4*>(&As[cur][kk][ty * 8]);
      *reinterpret_cast<float4*>(&a[4]) = *reinterpret_cast<const float4*>(&As[cur][kk][ty * 8 + 4]);
      *reinterpret_cast<float4*>(&b[0]) = *reinterpret_cast<const float4*>(&Bs[cur][kk][tx * 8]);
      *reinterpret_cast<float4*>(&b[4]) = *reinterpret_cast<const float4*>(&Bs[cur][kk][tx * 8 + 4]);
#pragma unroll
      for (int i = 0; i < 8; i++)
#pragma unroll
        for (int j = 0; j < 8; j++) acc[i][j] = fmaf(a[i], b[j], acc[i][j]);
    }
    if (hasNext) {
      store(cur ^ 1, 0, aP0, bP0);
      store(cur ^ 1, 1, aP1, bP1);
    }
    __syncthreads();
  }

#pragma unroll
  for (int i = 0; i < 8; i++) {
#pragma unroll
    for (int j = 0; j < 8; j++) {
      int m = bm * 128 + ty * 8 + i;
      int nn = bn * 128 + tx * 8 + j;
      int gate = nn >> 9, ju = nn & 511;
      float o = 0.0f;
      if (ju < 500) {
        int r = gate * 500 + ju;
        o = acc[i][j] + bih[dir * 2000 + r] + bhh[dir * 2000 + r];
      }
      G[((size_t)dir * T_SEQ + m) * 2048 + nn] = o;
    }
  }
}

__device__ __forceinline__ unsigned long long pack_hv(unsigned tag, float h) {
  return (unsigned long long)tag | ((unsigned long long)__float_as_uint(h) << 32);
}

__device__ __forceinline__ float fsig(float x) {
  float e = __expf(-x);
  return __builtin_amdgcn_rcpf(1.0f + e);
}
__device__ __forceinline__ float ftanhf(float x) {
  return fmaf(2.0f, fsig(x + x), -1.0f);
}

__global__ void hinit_k(const float* __restrict__ h0, int layer,
                        unsigned long long* __restrict__ hcomm,
                        int* __restrict__ progq) {
  int i = blockIdx.x * blockDim.x + threadIdx.x;   // 0..2047
  if (i < 64) progq[i] = -1;          // prog[2][32] = -1
  if (i == 64) progq[64] = 0;         // ticket = 0
  int dir = i >> 10, par = (i >> 9) & 1, j = i & 511;
  unsigned long long v;
  if (par == 0) {
    float h = (j < 500) ? h0[(layer * 2 + dir) * 500 + j] : 0.0f;
    v = pack_hv(0u, h);
  } else {
    v = 0xFFFFFFFFull;   // sentinel tag, value 0
  }
  hcomm[(size_t)(dir * 2 + par) * HPAD + j] = v;
}

// ===================== MERGED: lstm L0 + gin-L1 GEMM workers =====================
// Grid 256 x 1024. Blocks 0..63: R13 lstm (layer 0) + RELEASE prog publish /32 steps.
// Blocks 64..255: workers pulling 256x128 gin-L1 tiles off an atomic ticket queue,
// ACQUIRE-gated on prog. Middle-out bm order matches row readiness max(R+255, 4095-R).
__global__ __launch_bounds__(1024)
__attribute__((amdgpu_waves_per_eu(4, 4)))
void lstm_gemm_k(
    const float* __restrict__ whh_base,   // [2][2000][500]   (layer 0)
    const float* __restrict__ gin,        // [2][4096][2048]  L0-read / L1-write (gated)
    const float* __restrict__ c0,         // [4][500]
    float* __restrict__ xout,             // x1 [4096][1024]
    unsigned long long* __restrict__ hcomm,
    int* __restrict__ progq,              // [64] prog + [1] ticket
    const float* __restrict__ wih1,       // [2][2000][1000]
    const float* __restrict__ bih1, const float* __restrict__ bhh1) {
  __shared__ float part[16][68];
  __shared__ float hbuf[16][32];
  __shared__ float wAs[16][256];
  __shared__ float wBs[16][128];
  __shared__ int sTicket;

  const int tid = threadIdx.x;
  float* ginw = (float*)gin;

  if (blockIdx.x < 64) {
    // ---------------- lstm branch (R13-proven + prog publish) ----------------
    const int dir = blockIdx.x >> 5;
    const int wgd = blockIdx.x & 31;
    const int w = tid >> 6;
    const int lane = tid & 63;

    const int gate = lane >> 4;
    const int ul   = lane & 15;
    const int j    = wgd * 16 + ul;
    const int row  = gate * 500 + j;

    float wreg[32];
    const float* Wd = whh_base + (size_t)dir * 2000 * 500;
#pragma unroll
    for (int i = 0; i < 32; i++) {
      int k = w * 32 + i;
      wreg[i] = (j < 500 && k < 500) ? Wd[(size_t)row * 500 + k] : 0.0f;
    }
#pragma unroll
    for (int i = 0; i < 32; i++) asm volatile("" : "+v"(wreg[i]));

    float c = 0.0f;
    if (w == 0 && lane < 16 && j < 500) c = c0[(0 * 2 + dir) * 500 + j];

    unsigned long long* hcd = hcomm + (size_t)dir * 2 * HPAD;
    bool dead = false;

    for (int t = 0; t < T_SEQ; t++) {
      const int t_in = (dir == 0) ? t : (T_SEQ - 1 - t);

      float gi = 0.0f;
      if (w == 0) {
        const float* gb = gin + ((size_t)dir * T_SEQ + t_in) * 2048;
        gi = gb[gate * 512 + j];
      }

      unsigned long long v = 0;
      if (!dead) {
        const unsigned long long* hp =
            hcd + (size_t)(t & 1) * HPAD + w * 32 + (lane & 31);
        int guard = 0;
        for (;;) {
          v = __hip_atomic_load(hp, __ATOMIC_RELAXED, __HIP_MEMORY_SCOPE_AGENT);
          if (__all((int)((unsigned)v == (unsigned)t))) break;
          if (++guard > (1 << 22)) { dead = true; break; }
        }
      }
      float hval = __uint_as_float((unsigned)(v >> 32));

      if (lane < 32) hbuf[w][lane] = hval;
      float a = 0.0f;
#pragma unroll
      for (int b = 0; b < 8; b++) {
        float4 hv = *reinterpret_cast<const float4*>(&hbuf[w][b * 4]);
        a = fmaf(wreg[b * 4 + 0], hv.x, a);
        a = fmaf(wreg[b * 4 + 1], hv.y, a);
        a = fmaf(wreg[b * 4 + 2], hv.z, a);
        a = fmaf(wreg[b * 4 + 3], hv.w, a);
      }
      part[w][lane] = a;
      __syncthreads();

      if (w == 0) {
        __builtin_amdgcn_s_setprio(1);
        float p0 = part[0][lane] + part[1][lane];
        float p1 = part[2][lane] + part[3][lane];
        float p2 = part[4][lane] + part[5][lane];
        float p3 = part[6][lane] + part[7][lane];
        float p4 = part[8][lane] + part[9][lane];
        float p5 = part[10][lane] + part[11][lane];
        float p6 = part[12][lane] + part[13][lane];
        float p7 = part[14][lane] + part[15][lane];
        float q0 = p0 + p1, q1 = p2 + p3, q2 = p4 + p5, q3 = p6 + p7;
        float s = gi + ((q0 + q1) + (q2 + q3));
        float nl = (gate == 2) ? ftanhf(s) : fsig(s);
        float xf = __shfl(nl, lane + 16, 64);
        float xg = __shfl(nl, lane + 32, 64);
        float xo = __shfl(nl, lane + 48, 64);
        if (lane < 16) {
          c = xf * c + nl * xg;
          float h = xo * ftanhf(c);
          __hip_atomic_store(hcd + (size_t)((t + 1) & 1) * HPAD + j,
                             pack_hv((unsigned)(t + 1), h),
                             __ATOMIC_RELAXED, __HIP_MEMORY_SCOPE_AGENT);
          if (j < 500)
            xout[(size_t)t_in * 1024 + (size_t)dir * HPAD + j] = h;
          // progress publish: RELEASE orders this wave's xout stores (vmcnt drain).
          if (lane == 0 && (t & 31) == 31)
            __hip_atomic_store(&progq[dir * 32 + wgd], t,
                               __ATOMIC_RELEASE, __HIP_MEMORY_SCOPE_AGENT);
        }
        __builtin_amdgcn_s_setprio(0);
      }
    }
    return;
  }

  // ---------------- worker branch: gin L1 tiles (256 rows x 128 cols) ----------------
  const int ty = tid >> 4, tx = tid & 15;   // ty 0..63, tx 0..15
  for (;;) {
    if (tid == 0) sTicket = atomicAdd(&progq[64], 1);
    __syncthreads();
    int q = sTicket;
    __syncthreads();                        // sTicket consumed before next overwrite
    if (q >= 512) break;
    int r = q >> 5;                         // bm readiness rank
    int bm = (r & 1) ? 8 + (r >> 1) : 7 - (r >> 1);
    int dir = (q >> 4) & 1;
    int bn = q & 15;
    int R0 = bm * 256;

    // gate on progress (wave0 spins, others park at the barrier)
    if (tid < 64) {
      int thr = (tid < 32) ? (R0 + 255) : (4095 - R0);
      const int* pp = progq + tid;          // [0..31]=fwd, [32..63]=bwd
      int guard = 0;
      for (;;) {
        int pv = __hip_atomic_load(pp, __ATOMIC_ACQUIRE, __HIP_MEMORY_SCOPE_AGENT);
        if (__all(pv >= thr)) break;
        __builtin_amdgcn_s_sleep(8);
        if (++guard > (1 << 24)) break;     // backstop; unreachable with co-residency
      }
    }
    __syncthreads();

    const float* W = wih1 + (size_t)dir * 2000 * 1000;
    float acc[4][8] = {};
    for (int k0 = 0; k0 < 1024; k0 += 16) {
      {
        int m = tid >> 2, kc = (tid & 3) * 4;
        float4 av = *reinterpret_cast<const float4*>(
            &xout[(size_t)(R0 + m) * 1024 + k0 + kc]);
        wAs[kc + 0][m] = av.x; wAs[kc + 1][m] = av.y;
        wAs[kc + 2][m] = av.z; wAs[kc + 3][m] = av.w;
      }
      if (tid < 512) {
        int n = tid >> 2, kc = (tid & 3) * 4;
        int nn = bn * 128 + n;
        int gate = nn >> 9, j = nn & 511;
        int k = k0 + kc;
        int jk = k & 511, half = k >> 9;
        float4 bv = {0.f, 0.f, 0.f, 0.f};
        if (j < 500 && jk < 500)
          bv = *reinterpret_cast<const float4*>(
              &W[(size_t)(gate * 500 + j) * 1000 + half * 500 + jk]);
        wBs[kc + 0][n] = bv.x; wBs[kc + 1][n] = bv.y;
        wBs[kc + 2][n] = bv.z; wBs[kc + 3][n] = bv.w;
      }
      __syncthreads();
#pragma unroll
      for (int kk = 0; kk < 16; kk++) {
        float a[4], b[8];
        *reinterpret_cast<float4*>(&a[0]) = *reinterpret_cast<const float4*>(&wAs[kk][ty * 4]);
        *reinterpret_cast<float4*>(&b[0]) = *reinterpret_cast<const float4*>(&wBs[kk][tx * 8]);
        *reinterpret_cast<float4*>(&b[4]) = *reinterpret_cast<const float4*>(&wBs[kk][tx * 8 + 4]);
#pragma unroll
        for (int i = 0; i < 4; i++)
#pragma unroll
          for (int jj = 0; jj < 8; jj++) acc[i][jj] = fmaf(a[i], b[jj], acc[i][jj]);
      }
      __syncthreads();
    }
#pragma unroll
    for (int i = 0; i < 4; i++) {
#pragma unroll
      for (int jj = 0; jj < 8; jj++) {
        int t = R0 + ty * 4 + i;
        int nn = bn * 128 + tx * 8 + jj;
        int gate = nn >> 9, ju = nn & 511;
        float o = 0.0f;
        if (ju < 500) {
          int rr = gate * 500 + ju;
          o = acc[i][jj] + bih1[dir * 2000 + rr] + bhh1[dir * 2000 + rr];
        }
        ginw[((size_t)dir * T_SEQ + t) * 2048 + nn] = o;
      }
    }
  }
}

// Plain R13 lstm for layer 1 (proven).
__global__ __launch_bounds__(1024)
__attribute__((amdgpu_waves_per_eu(4, 4)))
void lstm_k(
    const float* __restrict__ whh_base, const float* __restrict__ gin,
    const float* __restrict__ c0, float* __restrict__ xout,
    unsigned long long* __restrict__ hcomm, int layer) {
  __shared__ float part[16][68];
  __shared__ float hbuf[16][32];

  const int tid = threadIdx.x;
  const int dir = blockIdx.x >> 5;
  const int wgd = blockIdx.x & 31;
  const int w = tid >> 6;
  const int lane = tid & 63;

  const int gate = lane >> 4;
  const int ul   = lane & 15;
  const int j    = wgd * 16 + ul;
  const int row  = gate * 500 + j;

  float wreg[32];
  const float* Wd = whh_base + (size_t)dir * 2000 * 500;
#pragma unroll
  for (int i = 0; i < 32; i++) {
    int k = w * 32 + i;
    wreg[i] = (j < 500 && k < 500) ? Wd[(size_t)row * 500 + k] : 0.0f;
  }
#pragma unroll
  for (int i = 0; i < 32; i++) asm volatile("" : "+v"(wreg[i]));

  float c = 0.0f;
  if (w == 0 && lane < 16 && j < 500) c = c0[(layer * 2 + dir) * 500 + j];

  unsigned long long* hcd = hcomm + (size_t)dir * 2 * HPAD;
  bool dead = false;

  for (int t = 0; t < T_SEQ; t++) {
    const int t_in = (dir == 0) ? t : (T_SEQ - 1 - t);

    float gi = 0.0f;
    if (w == 0) {
      const float* gb = gin + ((size_t)dir * T_SEQ + t_in) * 2048;
      gi = gb[gate * 512 + j];
    }

    unsigned long long v = 0;
    if (!dead) {
      const unsigned long long* hp =
          hcd + (size_t)(t & 1) * HPAD + w * 32 + (lane & 31);
      int guard = 0;
      for (;;) {
        v = __hip_atomic_load(hp, __ATOMIC_RELAXED, __HIP_MEMORY_SCOPE_AGENT);
        if (__all((int)((unsigned)v == (unsigned)t))) break;
        if (++guard > (1 << 22)) { dead = true; break; }
      }
    }
    float hval = __uint_as_float((unsigned)(v >> 32));

    if (lane < 32) hbuf[w][lane] = hval;
    float a = 0.0f;
#pragma unroll
    for (int b = 0; b < 8; b++) {
      float4 hv = *reinterpret_cast<const float4*>(&hbuf[w][b * 4]);
      a = fmaf(wreg[b * 4 + 0], hv.x, a);
      a = fmaf(wreg[b * 4 + 1], hv.y, a);
      a = fmaf(wreg[b * 4 + 2], hv.z, a);
      a = fmaf(wreg[b * 4 + 3], hv.w, a);
    }
    part[w][lane] = a;
    __syncthreads();

    if (w == 0) {
      __builtin_amdgcn_s_setprio(1);
      float p0 = part[0][lane] + part[1][lane];
      float p1 = part[2][lane] + part[3][lane];
      float p2 = part[4][lane] + part[5][lane];
      float p3 = part[6][lane] + part[7][lane];
      float p4 = part[8][lane] + part[9][lane];
      float p5 = part[10][lane] + part[11][lane];
      float p6 = part[12][lane] + part[13][lane];
      float p7 = part[14][lane] + part[15][lane];
      float q0 = p0 + p1, q1 = p2 + p3, q2 = p4 + p5, q3 = p6 + p7;
      float s = gi + ((q0 + q1) + (q2 + q3));
      float nl = (gate == 2) ? ftanhf(s) : fsig(s);
      float xf = __shfl(nl, lane + 16, 64);
      float xg = __shfl(nl, lane + 32, 64);
      float xo = __shfl(nl, lane + 48, 64);
      if (lane < 16) {
        c = xf * c + nl * xg;
        float h = xo * ftanhf(c);
        __hip_atomic_store(hcd + (size_t)((t + 1) & 1) * HPAD + j,
                           pack_hv((unsigned)(t + 1), h),
                           __ATOMIC_RELAXED, __HIP_MEMORY_SCOPE_AGENT);
        if (j < 500)
          xout[(size_t)t_in * 1024 + (size_t)dir * HPAD + j] = h;
      }
      __builtin_amdgcn_s_setprio(0);
    }
  }
}

// feats[t][tag] = sum_k x2[t][k]*w_out[tag][k_real] + b_out[tag]
__global__ __launch_bounds__(256) void feats_k(
    const float* __restrict__ x2, const float* __restrict__ w_out,
    const float* __restrict__ b_out, float* __restrict__ feats) {
  int tid = threadIdx.x;
  int tag = tid & 15, tl = tid >> 4;
  int t = blockIdx.x * 16 + tl;
  float a0 = 0.0f, a1 = 0.0f, a2 = 0.0f, a3 = 0.0f;
  for (int k = 0; k < 1024; k += 4) {
    int jk = k & 511;
    const float* xr = x2 + (size_t)t * 1024 + k;
    const float* wr = w_out + tag * 1000 + (k >> 9) * 500 + jk;
    if (jk + 3 < 500) {
      a0 = fmaf(xr[0], wr[0], a0);
      a1 = fmaf(xr[1], wr[1], a1);
      a2 = fmaf(xr[2], wr[2], a2);
      a3 = fmaf(xr[3], wr[3], a3);
    } else if (jk < 500) {
#pragma unroll
      for (int e = 0; e < 4; e++)
        if (jk + e < 500) a0 = fmaf(xr[e], wr[e], a0);
    }
  }
  feats[t * 16 + tag] = ((a0 + a1) + (a2 + a3)) + b_out[tag];
}

// Viterbi: one wave. lane = pg*16 + tag. Tree argmax, np.argmax tie-break.
__global__ __launch_bounds__(64) void viterbi_k(
    const float* __restrict__ feats, const float* __restrict__ trans,
    int* __restrict__ bptr, float* __restrict__ out) {
  int tid = threadIdx.x;
  int tag = tid & 15, pg = tid >> 4;
  float tr0 = trans[tag * 16 + pg * 4 + 0];
  float tr1 = trans[tag * 16 + pg * 4 + 1];
  float tr2 = trans[tag * 16 + pg * 4 + 2];
  float tr3 = trans[tag * 16 + pg * 4 + 3];
  float s = (tag == 14) ? 0.0f : -10000.0f;   // START=14
  float ft = feats[tag];
  for (int t = 0; t < T_SEQ; t++) {
    float ftn = (t + 1 < T_SEQ) ? feats[(t + 1) * 16 + tag] : 0.0f;
    float c0 = __shfl(s, pg * 4 + 0, 64) + tr0;
    float c1 = __shfl(s, pg * 4 + 1, 64) + tr1;
    float c2 = __shfl(s, pg * 4 + 2, 64) + tr2;
    float c3 = __shfl(s, pg * 4 + 3, 64) + tr3;
    float bv = c0; int bi = pg * 4;
    if (c1 > bv) { bv = c1; bi = pg * 4 + 1; }
    if (c2 > bv) { bv = c2; bi = pg * 4 + 2; }
    if (c3 > bv) { bv = c3; bi = pg * 4 + 3; }
    float ov = __shfl_xor(bv, 16, 64); int oi = __shfl_xor(bi, 16, 64);
    if (ov > bv || (ov == bv && oi < bi)) { bv = ov; bi = oi; }
    ov = __shfl_xor(bv, 32, 64); oi = __shfl_xor(bi, 32, 64);
    if (ov > bv || (ov == bv && oi < bi)) { bv = ov; bi = oi; }
    s = bv + ft;
    ft = ftn;
    if (pg == 0) bptr[t * 16 + tag] = bi;
  }
  s += trans[15 * 16 + tag];                   // STOP=15
  float bv = s; int bi = tag;
  for (int mask = 1; mask < 16; mask <<= 1) {
    float ov = __shfl_xor(bv, mask, 16); int oi = __shfl_xor(bi, mask, 16);
    if (ov > bv || (ov == bv && oi < bi)) { bv = ov; bi = oi; }
  }
  if (tid == 0) out[0] = bv;
  int bt = bi;
  for (int i = tid; i < T_SEQ - 1; i += 64)
    out[1 + i] = (float)bptr[(i + 1) * 16 + bt];
  if (tid == 0) out[T_SEQ] = (float)bt;
}

extern "C" void kernel_launch(void* const* d_in, const int* in_sizes, int n_in,
                              void* d_out, int out_size, void* d_ws, size_t ws_size,
                              hipStream_t stream) {
  const int*   sent  = (const int*)d_in[0];
  const float* embed = (const float*)d_in[1];
  const float* wih0  = (const float*)d_in[2];
  const float* whh0  = (const float*)d_in[3];
  const float* bih0  = (const float*)d_in[4];
  const float* bhh0  = (const float*)d_in[5];
  const float* wih1  = (const float*)d_in[6];
  const float* whh1  = (const float*)d_in[7];
  const float* bih1  = (const float*)d_in[8];
  const float* bhh1  = (const float*)d_in[9];
  const float* w_out = (const float*)d_in[10];
  const float* b_out = (const float*)d_in[11];
  const float* trans = (const float*)d_in[12];
  const float* h0    = (const float*)d_in[13];
  const float* c0    = (const float*)d_in[14];
  float* out = (float*)d_out;

  char* ws = (char*)d_ws;
  int*   progq = (int*)(ws + 0);          // [64] prog + [1] ticket (dead x0 region)
  float* x1    = (float*)(ws + 8388608);
  float* x2    = (float*)(ws + 25165824);
  float* gin   = (float*)(ws + 41943040);
  float* feats = (float*)(ws + 109051904);
  int*   bptr  = (int*)(ws + 109314048);
  unsigned long long* hcomm = (unsigned long long*)(ws + 109576192);

  // layer 0 input projection (embed fused)
  gin_gemm_k<<<dim3(16, 32, 2), 256, 0, stream>>>(nullptr, 512, sent, embed,
                                                  wih0, bih0, bhh0, 500, gin);
  hinit_k<<<2, 1024, 0, stream>>>(h0, 0, hcomm, progq);
  // MERGED: lstm L0 (blocks 0-63) + gin L1 workers (blocks 64-255)
  lstm_gemm_k<<<256, 1024, 0, stream>>>(whh0, gin, c0, x1, hcomm, progq,
                                        wih1, bih1, bhh1);

  // layer 1
  hinit_k<<<2, 1024, 0, stream>>>(h0, 1, hcomm, progq);
  lstm_k<<<64, 1024, 0, stream>>>(whh1, gin, c0, x2, hcomm, 1);

  // output projection + viterbi
  feats_k<<<T_SEQ / 16, 256, 0, stream>>>(x2, w_out, b_out, feats);
  viterbi_k<<<1, 64, 0, stream>>>(feats, trans, bptr, out);
}

// Round 17
// 12752.140 us; speedup vs baseline: 1.8772x; 1.8772x over previous
//
#include <hip/hip_runtime.h>

// LSTM-CRF on MI355X.
// Pipeline: gemm(gin L0, embed fused) -> lstm L0 -> gemm(gin L1) -> lstm L1 -> feats -> viterbi.
// Recurrence: round-13 PROVEN lstm, byte-identical (device-scope mailbox, simple spin).
// Dead ends (do not revisit): XCD-local comm (R2/3/14: sub-device-scope never visible
// cross-CU); pipelined polls (R11/12: vmcnt is issue-ordered, compiler drains);
// dual-dir interleave (R9: serializes parallel dirs); merged lstm+GEMM (R16: co-tenancy
// stretches the serial step 3.3x). Floor: per-step ~3,173cy = LLC RTT 1,400 + compute
// 1,300 + straggle; layers can't pipeline (bidirectional dependency) -> lstm ~10.8ms.
// Round-17: R13 + embed fused into the SIMPLE GEMM (R15 proved fusion correct but
// bundled it with a dbuf rewrite that regressed; this unbundles).

#define T_SEQ 4096
#define HPAD  512
#define NTAG  16

// ---------------- workspace layout (bytes) ----------------
// x1   : [4096][1024] f32  16777216  @ 8388608
// x2   : [4096][1024] f32  16777216  @ 25165824
// gin  : [2][4096][2048] f32 67108864 @ 41943040
// feats: [4096][16] f32     262144  @ 109051904
// bptr : [4096][16] i32     262144  @ 109314048
// hcomm: [2][2][512] u64     16384  @ 109576192

// G[dir][t][n] = sum_k A[t][k] * Wmap[dir][n][k] + bias[n]  (f32, 128x128 tile, 8x8/thread)
// L0 mode (sent != null): A[t][k] = embed_w[sent[t]][k] (k<500 else 0), KA=512.
// L1 mode (sent == null): A = x1 [4096][1024], KA=1024.
__global__ __launch_bounds__(256) void gin_gemm_k(
    const float* __restrict__ A, int KA,
    const int* __restrict__ sent, const float* __restrict__ embed_w,
    const float* __restrict__ wih, const float* __restrict__ bih,
    const float* __restrict__ bhh, int Kreal, float* __restrict__ G) {
  const int dir = blockIdx.z;
  const int bm = blockIdx.y, bn = blockIdx.x;
  const float* W = wih + (size_t)dir * 2000 * Kreal;

  __shared__ float As[16][128];
  __shared__ float Bs[16][128];
  __shared__ int   sSent[128];

  const int tid = threadIdx.x;
  const int tx = tid & 15, ty = tid >> 4;
  float acc[8][8] = {};

  if (sent) {
    if (tid < 128) sSent[tid] = sent[bm * 128 + tid];
    __syncthreads();
  }

  for (int k0 = 0; k0 < KA; k0 += 16) {
#pragma unroll
    for (int q = 0; q < 2; q++) {
      int f4 = tid + q * 256;              // 0..511
      int m = f4 >> 2, kc = (f4 & 3) * 4;
      int k = k0 + kc;
      float4 av;
      if (sent) {
        // k%4==0 -> k<=496 -> all 4 elements valid; embed rows are 2000B (16B-aligned)
        av = make_float4(0.f, 0.f, 0.f, 0.f);
        if (k < 500)
          av = *reinterpret_cast<const float4*>(&embed_w[(size_t)sSent[m] * 500 + k]);
      } else {
        av = *reinterpret_cast<const float4*>(A + (size_t)(bm * 128 + m) * KA + k);
      }
      As[kc + 0][m] = av.x; As[kc + 1][m] = av.y;
      As[kc + 2][m] = av.z; As[kc + 3][m] = av.w;
    }
#pragma unroll
    for (int q = 0; q < 2; q++) {
      int f4 = tid + q * 256;
      int n = f4 >> 2, kc = (f4 & 3) * 4;
      int nn = bn * 128 + n;
      int gate = nn >> 9, j = nn & 511;
      int k = k0 + kc;
      int jk = k & 511, half = k >> 9;
      // jk%4==0 -> jk<=496 -> all 4 valid; W row bases 16B-aligned (500/1000 f32 rows)
      float4 bv = {0.0f, 0.0f, 0.0f, 0.0f};
      if (j < 500 && jk < 500)
        bv = *reinterpret_cast<const float4*>(
            &W[(size_t)(gate * 500 + j) * Kreal + half * 500 + jk]);
      Bs[kc + 0][n] = bv.x; Bs[kc + 1][n] = bv.y;
      Bs[kc + 2][n] = bv.z; Bs[kc + 3][n] = bv.w;
    }
    __syncthreads();
#pragma unroll
    for (int kk = 0; kk < 16; kk++) {
      float a[8], b[8];
      *reinterpret_cast<float4*>(&a[0]) = *reinterpret_cast<const float4*>(&As[kk][ty * 8]);
      *reinterpret_cast<float4*>(&a[4]) = *reinterpret_cast<const float4*>(&As[kk][ty * 8 + 4]);
      *reinterpret_cast<float4*>(&b[0]) = *reinterpret_cast<const float4*>(&Bs[kk][tx * 8]);
      *reinterpret_cast<float4*>(&b[4]) = *reinterpret_cast<const float4*>(&Bs[kk][tx * 8 + 4]);
#pragma unroll
      for (int i = 0; i < 8; i++)
#pragma unroll
        for (int j = 0; j < 8; j++) acc[i][j] = fmaf(a[i], b[j], acc[i][j]);
    }
    __syncthreads();
  }
#pragma unroll
  for (int i = 0; i < 8; i++) {
#pragma unroll
    for (int j = 0; j < 8; j++) {
      int m = bm * 128 + ty * 8 + i;
      int nn = bn * 128 + tx * 8 + j;
      int gate = nn >> 9, ju = nn & 511;
      float o = 0.0f;
      if (ju < 500) {
        int r = gate * 500 + ju;
        o = acc[i][j] + bih[dir * 2000 + r] + bhh[dir * 2000 + r];
      }
      G[((size_t)dir * T_SEQ + m) * 2048 + nn] = o;
    }
  }
}

__device__ __forceinline__ unsigned long long pack_hv(unsigned tag, float h) {
  return (unsigned long long)tag | ((unsigned long long)__float_as_uint(h) << 32);
}

// fast sigmoid/tanh: v_exp_f32 + v_rcp_f32, branch-free, saturates correctly.
__device__ __forceinline__ float fsig(float x) {
  float e = __expf(-x);
  return __builtin_amdgcn_rcpf(1.0f + e);
}
__device__ __forceinline__ float ftanhf(float x) {
  return fmaf(2.0f, fsig(x + x), -1.0f);
}

__global__ void hinit_k(const float* __restrict__ h0, int layer,
                        unsigned long long* __restrict__ hcomm) {
  int i = blockIdx.x * blockDim.x + threadIdx.x;   // 0..2047
  int dir = i >> 10, par = (i >> 9) & 1, j = i & 511;
  unsigned long long v;
  if (par == 0) {
    float h = (j < 500) ? h0[(layer * 2 + dir) * 500 + j] : 0.0f;
    v = pack_hv(0u, h);
  } else {
    v = 0xFFFFFFFFull;   // sentinel tag, value 0
  }
  hcomm[(size_t)(dir * 2 + par) * HPAD + j] = v;
}

// Persistent recurrence kernel: 64 WGs x 1024 threads; WG = (dir = blockIdx>>5,
// wgd = blockIdx&31) owns units [wgd*16, wgd*16+16)  (64 rows = 4 gates x 16 units).
// Wave w owns k-slice [w*32, w*32+32); lane owns ONE row (gate=lane>>4, unit=lane&15).
// One barrier per step; wave0 sums 16 partials per row (pairwise tree), fast gates,
// publishes. Poll: simple spin (proven optimal). BYTE-IDENTICAL to round 13.
__global__ __launch_bounds__(1024)
__attribute__((amdgpu_waves_per_eu(4, 4)))
void lstm_k(
    const float* __restrict__ whh_base,   // [2][2000][500]
    const float* __restrict__ gin,        // [2][4096][2048]
    const float* __restrict__ c0,         // [4][500]
    float* __restrict__ xout,             // [4096][1024]
    unsigned long long* __restrict__ hcomm, // [2][2][512]
    int layer) {
  __shared__ float part[16][68];          // pad 68: conflict-free on both patterns
  __shared__ float hbuf[16][32];

  const int tid = threadIdx.x;
  const int dir = blockIdx.x >> 5;
  const int wgd = blockIdx.x & 31;        // unit block [wgd*16, wgd*16+16)
  const int w = tid >> 6;
  const int lane = tid & 63;

  const int gate = lane >> 4;             // my row's gate (0=i,1=f,2=g,3=o)
  const int ul   = lane & 15;             // my row's local unit
  const int j    = wgd * 16 + ul;         // global unit (0..511)
  const int row  = gate * 500 + j;

  // ---- load recurrent weights into registers (1 row x 32 k per lane) ----
  float wreg[32];
  const float* Wd = whh_base + (size_t)dir * 2000 * 500;
#pragma unroll
  for (int i = 0; i < 32; i++) {
    int k = w * 32 + i;
    wreg[i] = (j < 500 && k < 500) ? Wd[(size_t)row * 500 + k] : 0.0f;
  }
#pragma unroll
  for (int i = 0; i < 32; i++) asm volatile("" : "+v"(wreg[i]));

  // wave0 lanes<16: persistent cell state (one unit per lane)
  float c = 0.0f;
  if (w == 0 && lane < 16 && j < 500) c = c0[(layer * 2 + dir) * 500 + j];

  unsigned long long* hcd = hcomm + (size_t)dir * 2 * HPAD;
  bool dead = false;

  for (int t = 0; t < T_SEQ; t++) {
    const int t_in = (dir == 0) ? t : (T_SEQ - 1 - t);

    // prefetch input-projection gate value for my row (latency hidden under poll)
    float gi = 0.0f;
    if (w == 0) {
      const float* gb = gin + ((size_t)dir * T_SEQ + t_in) * 2048;
      gi = gb[gate * 512 + j];
    }

    // ---- poll my wave's h k-slice (tag==t), device-scope, simple spin ----
    unsigned long long v = 0;
    if (!dead) {
      const unsigned long long* hp =
          hcd + (size_t)(t & 1) * HPAD + w * 32 + (lane & 31);
      int guard = 0;
      for (;;) {
        v = __hip_atomic_load(hp, __ATOMIC_RELAXED, __HIP_MEMORY_SCOPE_AGENT);
        if (__all((int)((unsigned)v == (unsigned)t))) break;
        if (++guard > (1 << 22)) { dead = true; break; }   // bail, never hang
      }
    }
    float hval = __uint_as_float((unsigned)(v >> 32));

    // ---- broadcast h within the wave via LDS, matvec partial for my row ----
    if (lane < 32) hbuf[w][lane] = hval;   // same-wave RAW, ordered by lgkmcnt
    float a = 0.0f;
#pragma unroll
    for (int b = 0; b < 8; b++) {
      float4 hv = *reinterpret_cast<const float4*>(&hbuf[w][b * 4]);
      a = fmaf(wreg[b * 4 + 0], hv.x, a);
      a = fmaf(wreg[b * 4 + 1], hv.y, a);
      a = fmaf(wreg[b * 4 + 2], hv.z, a);
      a = fmaf(wreg[b * 4 + 3], hv.w, a);
    }
    part[w][lane] = a;
    __syncthreads();   // the ONLY barrier per step

    // ---- wave0: pairwise tree-sum of 16 partials, fast gates, publish ----
    if (w == 0) {
      __builtin_amdgcn_s_setprio(1);       // win issue arbitration vs spinning waves
      float p0 = part[0][lane] + part[1][lane];
      float p1 = part[2][lane] + part[3][lane];
      float p2 = part[4][lane] + part[5][lane];
      float p3 = part[6][lane] + part[7][lane];
      float p4 = part[8][lane] + part[9][lane];
      float p5 = part[10][lane] + part[11][lane];
      float p6 = part[12][lane] + part[13][lane];
      float p7 = part[14][lane] + part[15][lane];
      float q0 = p0 + p1, q1 = p2 + p3, q2 = p4 + p5, q3 = p6 + p7;
      float s = gi + ((q0 + q1) + (q2 + q3));
      float nl = (gate == 2) ? ftanhf(s) : fsig(s);
      float xf = __shfl(nl, lane + 16, 64);
      float xg = __shfl(nl, lane + 32, 64);
      float xo = __shfl(nl, lane + 48, 64);
      if (lane < 16) {
        c = xf * c + nl * xg;              // nl here is xi (gate 0)
        float h = xo * ftanhf(c);
        // publish FIRST (starts the LLC trip), then the xout store
        __hip_atomic_store(hcd + (size_t)((t + 1) & 1) * HPAD + j,
                           pack_hv((unsigned)(t + 1), h),
                           __ATOMIC_RELAXED, __HIP_MEMORY_SCOPE_AGENT);
        if (j < 500)
          xout[(size_t)t_in * 1024 + (size_t)dir * HPAD + j] = h;
      }
      __builtin_amdgcn_s_setprio(0);
    }
  }
}

// feats[t][tag] = sum_k x2[t][k]*w_out[tag][k_real] + b_out[tag]
__global__ __launch_bounds__(256) void feats_k(
    const float* __restrict__ x2, const float* __restrict__ w_out,
    const float* __restrict__ b_out, float* __restrict__ feats) {
  int tid = threadIdx.x;
  int tag = tid & 15, tl = tid >> 4;
  int t = blockIdx.x * 16 + tl;
  float a0 = 0.0f, a1 = 0.0f, a2 = 0.0f, a3 = 0.0f;
  for (int k = 0; k < 1024; k += 4) {
    int jk = k & 511;
    const float* xr = x2 + (size_t)t * 1024 + k;
    const float* wr = w_out + tag * 1000 + (k >> 9) * 500 + jk;
    if (jk + 3 < 500) {
      a0 = fmaf(xr[0], wr[0], a0);
      a1 = fmaf(xr[1], wr[1], a1);
      a2 = fmaf(xr[2], wr[2], a2);
      a3 = fmaf(xr[3], wr[3], a3);
    } else if (jk < 500) {
#pragma unroll
      for (int e = 0; e < 4; e++)
        if (jk + e < 500) a0 = fmaf(xr[e], wr[e], a0);
    }
  }
  feats[t * 16 + tag] = ((a0 + a1) + (a2 + a3)) + b_out[tag];
}

// Viterbi: one wave. lane = pg*16 + tag (pg = prev-group of 4). Tree argmax with
// np.argmax tie-break (smallest prev index). feats prefetched one step ahead.
__global__ __launch_bounds__(64) void viterbi_k(
    const float* __restrict__ feats, const float* __restrict__ trans,
    int* __restrict__ bptr, float* __restrict__ out) {
  int tid = threadIdx.x;
  int tag = tid & 15, pg = tid >> 4;
  float tr0 = trans[tag * 16 + pg * 4 + 0];
  float tr1 = trans[tag * 16 + pg * 4 + 1];
  float tr2 = trans[tag * 16 + pg * 4 + 2];
  float tr3 = trans[tag * 16 + pg * 4 + 3];
  float s = (tag == 14) ? 0.0f : -10000.0f;   // START=14
  float ft = feats[tag];                       // t=0 prefetch
  for (int t = 0; t < T_SEQ; t++) {
    float ftn = (t + 1 < T_SEQ) ? feats[(t + 1) * 16 + tag] : 0.0f;
    float c0 = __shfl(s, pg * 4 + 0, 64) + tr0;
    float c1 = __shfl(s, pg * 4 + 1, 64) + tr1;
    float c2 = __shfl(s, pg * 4 + 2, 64) + tr2;
    float c3 = __shfl(s, pg * 4 + 3, 64) + tr3;
    float bv = c0; int bi = pg * 4;
    if (c1 > bv) { bv = c1; bi = pg * 4 + 1; }
    if (c2 > bv) { bv = c2; bi = pg * 4 + 2; }
    if (c3 > bv) { bv = c3; bi = pg * 4 + 3; }
    float ov = __shfl_xor(bv, 16, 64); int oi = __shfl_xor(bi, 16, 64);
    if (ov > bv || (ov == bv && oi < bi)) { bv = ov; bi = oi; }
    ov = __shfl_xor(bv, 32, 64); oi = __shfl_xor(bi, 32, 64);
    if (ov > bv || (ov == bv && oi < bi)) { bv = ov; bi = oi; }
    s = bv + ft;
    ft = ftn;
    if (pg == 0) bptr[t * 16 + tag] = bi;
  }
  s += trans[15 * 16 + tag];                   // STOP=15
  float bv = s; int bi = tag;
  for (int mask = 1; mask < 16; mask <<= 1) {
    float ov = __shfl_xor(bv, mask, 16); int oi = __shfl_xor(bi, mask, 16);
    if (ov > bv || (ov == bv && oi < bi)) { bv = ov; bi = oi; }
  }
  if (tid == 0) out[0] = bv;
  int bt = bi;                                 // identical in all lanes
  for (int i = tid; i < T_SEQ - 1; i += 64)
    out[1 + i] = (float)bptr[(i + 1) * 16 + bt];
  if (tid == 0) out[T_SEQ] = (float)bt;
}

extern "C" void kernel_launch(void* const* d_in, const int* in_sizes, int n_in,
                              void* d_out, int out_size, void* d_ws, size_t ws_size,
                              hipStream_t stream) {
  const int*   sent  = (const int*)d_in[0];
  const float* embed = (const float*)d_in[1];
  const float* wih0  = (const float*)d_in[2];
  const float* whh0  = (const float*)d_in[3];
  const float* bih0  = (const float*)d_in[4];
  const float* bhh0  = (const float*)d_in[5];
  const float* wih1  = (const float*)d_in[6];
  const float* whh1  = (const float*)d_in[7];
  const float* bih1  = (const float*)d_in[8];
  const float* bhh1  = (const float*)d_in[9];
  const float* w_out = (const float*)d_in[10];
  const float* b_out = (const float*)d_in[11];
  const float* trans = (const float*)d_in[12];
  const float* h0    = (const float*)d_in[13];
  const float* c0    = (const float*)d_in[14];
  float* out = (float*)d_out;

  char* ws = (char*)d_ws;
  float* x1    = (float*)(ws + 8388608);
  float* x2    = (float*)(ws + 25165824);
  float* gin   = (float*)(ws + 41943040);
  float* feats = (float*)(ws + 109051904);
  int*   bptr  = (int*)(ws + 109314048);
  unsigned long long* hcomm = (unsigned long long*)(ws + 109576192);

  // layer 0 (embed fused into GEMM A-staging)
  gin_gemm_k<<<dim3(16, 32, 2), 256, 0, stream>>>(nullptr, 512, sent, embed,
                                                  wih0, bih0, bhh0, 500, gin);
  hinit_k<<<2, 1024, 0, stream>>>(h0, 0, hcomm);
  lstm_k<<<64, 1024, 0, stream>>>(whh0, gin, c0, x1, hcomm, 0);

  // layer 1
  gin_gemm_k<<<dim3(16, 32, 2), 256, 0, stream>>>(x1, 1024, nullptr, nullptr,
                                                  wih1, bih1, bhh1, 1000, gin);
  hinit_k<<<2, 1024, 0, stream>>>(h0, 1, hcomm);
  lstm_k<<<64, 1024, 0, stream>>>(whh1, gin, c0, x2, hcomm, 1);

  // output projection + viterbi
  feats_k<<<T_SEQ / 16, 256, 0, stream>>>(x2, w_out, b_out, feats);
  viterbi_k<<<1, 64, 0, stream>>>(feats, trans, bptr, out);
}